// Round 16
// baseline (282.348 us; speedup 1.0000x reference)
//
#include <hip/hip_runtime.h>
#include <math.h>

#define BB 2
#define SS 2048
#define DD 1024
#define HH 16
#define DHH 64

typedef _Float16 f16;
typedef f16 f16x8 __attribute__((ext_vector_type(8)));
typedef f16 f16x4 __attribute__((ext_vector_type(4)));
typedef float f32x4 __attribute__((ext_vector_type(4)));
typedef float fvec4 __attribute__((ext_vector_type(4)));

#define LOG2E 1.4426950408889634f

static __device__ __forceinline__ f32x4 mfma16(f16x8 a, f16x8 b, f32x4 c) {
    return __builtin_amdgcn_mfma_f32_16x16x32_f16(a, b, c, 0, 0, 0);
}

// XOR bank swizzle (T2): col in f16 units; toggles byte bits 4..6.
#define SWZ(r, c) ((c) ^ (((r) & 7) << 3))

static __device__ __forceinline__ void gload_lds16(const void* g, void* l) {
    __builtin_amdgcn_global_load_lds(
        (const __attribute__((address_space(1))) void*)g,
        (__attribute__((address_space(3))) void*)l, 16, 0, 0);
}

// Raw barrier: no vmcnt drain (NT stores stay in flight).
static __device__ __forceinline__ void barrier_raw() {
    __builtin_amdgcn_sched_barrier(0);
    __builtin_amdgcn_s_barrier();
    __builtin_amdgcn_sched_barrier(0);
}
// Barrier publishing LDS writes: lgkmcnt(0) only, no vmcnt drain.
static __device__ __forceinline__ void barrier_lds() {
    asm volatile("s_waitcnt lgkmcnt(0)" ::: "memory");
    __builtin_amdgcn_s_barrier();
    __builtin_amdgcn_sched_barrier(0);
}

// ---------------- weight transpose + f32->f16 convert ----------------
__global__ __launch_bounds__(256) void wtrans_kernel(
    const float* __restrict__ w0, const float* __restrict__ w1,
    const float* __restrict__ w2, const float* __restrict__ w3,
    f16* __restrict__ o0, f16* __restrict__ o1,
    f16* __restrict__ o2, f16* __restrict__ o3)
{
    const float* src; f16* dst;
    switch (blockIdx.z) {
        case 0:  src = w0; dst = o0; break;
        case 1:  src = w1; dst = o1; break;
        case 2:  src = w2; dst = o2; break;
        default: src = w3; dst = o3; break;
    }
    __shared__ float t[64][65];
    const int tid = threadIdx.x;
    const int n0 = blockIdx.x * 64, k0 = blockIdx.y * 64;
    const int r = tid >> 4, c4 = (tid & 15) * 4;
    #pragma unroll
    for (int p = 0; p < 4; ++p) {
        int row = r + p * 16;
        fvec4 v = *(const fvec4*)&src[(size_t)(k0 + row) * DD + n0 + c4];
        #pragma unroll
        for (int j = 0; j < 4; ++j) t[row][c4 + j] = v[j];
    }
    __syncthreads();
    #pragma unroll
    for (int p = 0; p < 4; ++p) {
        int row = r + p * 16;  // n-local
        f16x4 v;
        #pragma unroll
        for (int j = 0; j < 4; ++j) v[j] = (f16)t[c4 + j][row];
        *(f16x4*)&dst[(size_t)(n0 + row) * DD + k0 + c4] = v;
    }
}

// ---------------- fused QKV projection GEMM (R7, unchanged) ----------------
__global__ __launch_bounds__(256) void gemm_qkv(
    const float* __restrict__ Aq, const float* __restrict__ Ak, const float* __restrict__ Av,
    const f16* __restrict__ Wqt, const f16* __restrict__ Wkt, const f16* __restrict__ Wvt,
    f16* __restrict__ oq, f16* __restrict__ ok, f16* __restrict__ ovt)
{
    const int K = DD;
    const int l = (blockIdx.x & 7) * 96 + (blockIdx.x >> 3);
    const int z  = (l % 96) / 32;
    const int mt = (l / 96) * 4 + (l % 32) / 8;
    const int nt = l % 8;

    const float* A; const f16* Bt; f16* C;
    switch (z) {
        case 0:  A = Aq; Bt = Wqt; C = oq; break;
        case 1:  A = Ak; Bt = Wkt; C = ok; break;
        default: A = Av; Bt = Wvt; C = ovt; break;
    }
    const int m0 = mt * 128, n0 = nt * 128;
    const int tid = threadIdx.x, lane = tid & 63;
    const int wm = (tid >> 7) & 1, wn = (tid >> 6) & 1;
    const int ln = lane & 15, lg = lane >> 4;

    __shared__ f16 As[128 * 64];
    __shared__ f16 Bs[128 * 64];

    f32x4 acc[4][4] = {};

    const int sr = tid >> 3;
    const int sc = (tid & 7) * 8;
    const int l8 = sr & 7;
    const int bsrc = ((tid & 7) ^ l8) * 8;
    const int ldsbase = (sr & ~7) * 64;

    for (int k0 = 0; k0 < K; k0 += 64) {
        #pragma unroll
        for (int p = 0; p < 4; ++p)
            gload_lds16(Bt + (size_t)(n0 + sr + p * 32) * K + k0 + bsrc,
                        &Bs[ldsbase + p * 32 * 64]);
        #pragma unroll
        for (int p = 0; p < 4; ++p) {
            int row = sr + p * 32;
            const float* s = A + (size_t)(m0 + row) * K + k0 + sc;
            fvec4 x0 = *(const fvec4*)s;
            fvec4 x1 = *(const fvec4*)(s + 4);
            f16x8 v;
            #pragma unroll
            for (int j = 0; j < 4; ++j) { v[j] = (f16)x0[j]; v[j + 4] = (f16)x1[j]; }
            *(f16x8*)&As[row * 64 + SWZ(row, sc)] = v;
        }
        __syncthreads();
        #pragma unroll
        for (int ks = 0; ks < 2; ++ks) {
            f16x8 af[4], bf[4];
            #pragma unroll
            for (int i = 0; i < 4; ++i) {
                int ra = wm * 64 + i * 16 + ln, rb = wn * 64 + i * 16 + ln;
                int cc = ks * 32 + lg * 8;
                af[i] = *(const f16x8*)&As[ra * 64 + SWZ(ra, cc)];
                bf[i] = *(const f16x8*)&Bs[rb * 64 + SWZ(rb, cc)];
            }
            __builtin_amdgcn_s_setprio(1);
            #pragma unroll
            for (int i = 0; i < 4; ++i)
                #pragma unroll
                for (int j = 0; j < 4; ++j)
                    acc[i][j] = mfma16(af[i], bf[j], acc[i][j]);
            __builtin_amdgcn_s_setprio(0);
        }
        __syncthreads();
    }

    const int vmode = (z == 2);
    #pragma unroll
    for (int i = 0; i < 4; ++i) {
        #pragma unroll
        for (int j = 0; j < 4; ++j) {
            if (vmode) {
                int m = m0 + wm * 64 + i * 16 + lg * 4;
                int n = n0 + wn * 64 + j * 16 + ln;
                int b = m >> 11, s = m & (SS - 1);
                int h = n >> 6, dh = n & 63;
                f16x4 v4;
                #pragma unroll
                for (int v = 0; v < 4; ++v) v4[v] = (f16)acc[i][j][v];
                *(f16x4*)&C[((size_t)((b * HH + h) * DHH + dh)) * SS + s] = v4;
            } else {
                #pragma unroll
                for (int v = 0; v < 4; ++v) {
                    int m = m0 + wm * 64 + i * 16 + lg * 4 + v;
                    int n = n0 + wn * 64 + j * 16 + ln;
                    int b = m >> 11, s = m & (SS - 1);
                    int h = n >> 6, dh = n & 63;
                    C[((size_t)((b * HH + h) * SS + s)) * DHH + dh] = (f16)acc[i][j][v];
                }
            }
        }
    }
}

// ---------------- final projection GEMM (R7, unchanged) ----------------
__global__ __launch_bounds__(256) void gemm_out(
    const f16* __restrict__ A, const f16* __restrict__ Bt,
    const float* __restrict__ bias, float* __restrict__ C)
{
    const int K = DD;
    const int l = (blockIdx.x & 7) * 32 + (blockIdx.x >> 3);
    const int mt = (l / 32) * 4 + (l % 32) / 8;
    const int nt = l % 8;
    const int m0 = mt * 128, n0 = nt * 128;
    const int tid = threadIdx.x, lane = tid & 63;
    const int wm = (tid >> 7) & 1, wn = (tid >> 6) & 1;
    const int ln = lane & 15, lg = lane >> 4;

    __shared__ f16 As[128 * 64];
    __shared__ f16 Bs[128 * 64];

    f32x4 acc[4][4] = {};

    const int sr = tid >> 3;
    const int l8 = sr & 7;
    const int bsrc = ((tid & 7) ^ l8) * 8;
    const int ldsbase = (sr & ~7) * 64;

    for (int k0 = 0; k0 < K; k0 += 64) {
        #pragma unroll
        for (int p = 0; p < 4; ++p) {
            gload_lds16(A + (size_t)(m0 + sr + p * 32) * K + k0 + bsrc,
                        &As[ldsbase + p * 32 * 64]);
            gload_lds16(Bt + (size_t)(n0 + sr + p * 32) * K + k0 + bsrc,
                        &Bs[ldsbase + p * 32 * 64]);
        }
        __syncthreads();
        #pragma unroll
        for (int ks = 0; ks < 2; ++ks) {
            f16x8 af[4], bf[4];
            #pragma unroll
            for (int i = 0; i < 4; ++i) {
                int ra = wm * 64 + i * 16 + ln, rb = wn * 64 + i * 16 + ln;
                int cc = ks * 32 + lg * 8;
                af[i] = *(const f16x8*)&As[ra * 64 + SWZ(ra, cc)];
                bf[i] = *(const f16x8*)&Bs[rb * 64 + SWZ(rb, cc)];
            }
            __builtin_amdgcn_s_setprio(1);
            #pragma unroll
            for (int i = 0; i < 4; ++i)
                #pragma unroll
                for (int j = 0; j < 4; ++j)
                    acc[i][j] = mfma16(af[i], bf[j], acc[i][j]);
            __builtin_amdgcn_s_setprio(0);
        }
        __syncthreads();
    }

    #pragma unroll
    for (int i = 0; i < 4; ++i)
        #pragma unroll
        for (int j = 0; j < 4; ++j)
            #pragma unroll
            for (int v = 0; v < 4; ++v) {
                int m = m0 + wm * 64 + i * 16 + lg * 4 + v;
                int n = n0 + wn * 64 + j * 16 + ln;
                C[(size_t)m * DD + n] = acc[i][j][v] + bias[n];
            }
}

// ---------------- fused attention (R15 base + rcp-form penalty) ------------
// Penalty applied as multiply AFTER exp: exp(s - log1p(d/S)) = exp(s)*S/(S+d),
// S cancels in normalization -> p = exp2(qk*SC + mask - cfix) * rcp(S+d).
// rcp(S+d) and d-math are independent of the MFMA result (hoist above it);
// critical chain shrinks from mfma->log->add->exp to mfma->fma->exp.
// Pass-1 uses 4 independent partial accumulators (serial fadd chain / 4).
__global__ __launch_bounds__(256, 4) void attn_kernel(
    const f16* __restrict__ qg, const f16* __restrict__ kg, const f16* __restrict__ vtg,
    const float* __restrict__ maskg, const float* __restrict__ peng,
    float* __restrict__ attn_out, f16* __restrict__ ctx_out)
{
    const int bid = blockIdx.x;
    const int wg = (bid & 7) * 128 + (bid >> 3);   // bijective XCD swizzle
    const int bh = wg >> 5;                        // 0..31
    const int b = bh >> 4, h = bh & 15;
    const int q0 = (wg & 31) * 64;

    const int tid = threadIdx.x, lane = tid & 63, wv = tid >> 6;  // wv 0..3
    const int ln = lane & 15, lg = lane >> 4;

    __shared__ f16 Kt[64 * 64];       // 8 KB K tile
    __shared__ f16 Vt[64 * 64];       // 8 KB V tile (pass 2)
    __shared__ f16 Ps[64 * 64];       // 8 KB P tile (wave-private rows)
    __shared__ f16 mrowh[SS];         // 4 KB  mask * (-1e9*log2e)

    for (int i = tid; i < SS; i += 256)
        mrowh[i] = (f16)fmaxf(maskg[b * SS + i] * (-1e9f * LOG2E), -60000.f);

    // Q fragment: lane holds Q[q0+wv*16+ln][lg*8 + j]
    const f16* qbase = qg + ((size_t)bh * SS + q0 + wv * 16 + ln) * DHH;
    f16x8 aq0 = *(const f16x8*)(qbase + lg * 8);
    f16x8 aq1 = *(const f16x8*)(qbase + 32 + lg * 8);

    const f16* kbase = kg + (size_t)bh * SS * DHH;
    const f16* vbase = vtg + (size_t)bh * DHH * SS;

    // reg staging (T14): K tile 64x64 (2 chunks/thread), V tile 64x64 (2/thread)
    const int krow = tid >> 3, kcol = (tid & 7) * 8;   // rows 0..31 (+32)
    f16x8 kst0, kst1, vst0, vst1;

    #define LOADK(kt) { kst0 = *(const f16x8*)(kbase + ((size_t)(kt) * 64 + krow) * DHH + kcol); \
                        kst1 = *(const f16x8*)(kbase + ((size_t)(kt) * 64 + krow + 32) * DHH + kcol); }
    #define WRITEK()  { *(f16x8*)&Kt[krow * 64 + SWZ(krow, kcol)] = kst0; \
                        *(f16x8*)&Kt[(krow + 32) * 64 + SWZ(krow + 32, kcol)] = kst1; }
    #define LOADV(kt) { vst0 = *(const f16x8*)(vbase + (size_t)krow * SS + (kt) * 64 + kcol); \
                        vst1 = *(const f16x8*)(vbase + (size_t)(krow + 32) * SS + (kt) * 64 + kcol); }
    #define WRITEV()  { *(f16x8*)&Vt[krow * 64 + SWZ(krow, kcol)] = vst0; \
                        *(f16x8*)&Vt[(krow + 32) * 64 + SWZ(krow + 32, kcol)] = vst1; }

    const int q = q0 + wv * 16 + ln;             // this lane's q row
    const float SC = 0.125f * LOG2E;             // score scale, log2 domain

    LOADK(0);
    WRITEK();
    __syncthreads();

    float lrun = 0.f;

    // ---- pass 1: l = sum exp2(s)*rcp(S+d); 32 K-tiles of 64 ----
    for (int kt = 0; kt < 32; ++kt) {
        if (kt < 31) LOADK(kt + 1);

        float s4[4] = {0.f, 0.f, 0.f, 0.f};
        #pragma unroll
        for (int sub = 0; sub < 4; ++sub) {
            int kr = sub * 16 + ln;
            f16x8 k0 = *(const f16x8*)&Kt[kr * 64 + SWZ(kr, lg * 8)];
            f16x8 k1 = *(const f16x8*)&Kt[kr * 64 + SWZ(kr, 32 + lg * 8)];
            const int kjb = kt * 64 + sub * 16 + lg * 4;
            f16x4 mr = *(const f16x4*)&mrowh[kjb];
            float rp[4];
            #pragma unroll
            for (int v = 0; v < 4; ++v) {
                int d = q - (kjb + v); d = d < 0 ? -d : d;
                rp[v] = __builtin_amdgcn_rcpf((float)(SS + d));
            }
            f32x4 sa = {0.f, 0.f, 0.f, 0.f};
            __builtin_amdgcn_s_setprio(1);
            sa = mfma16(k0, aq0, sa);
            sa = mfma16(k1, aq1, sa);
            __builtin_amdgcn_s_setprio(0);
            #pragma unroll
            for (int v = 0; v < 4; ++v)
                s4[v] += __builtin_amdgcn_exp2f(sa[v] * SC + (float)mr[v]) * rp[v];
        }
        float sum = (s4[0] + s4[1]) + (s4[2] + s4[3]);
        sum += __shfl_xor(sum, 16);
        sum += __shfl_xor(sum, 32);
        lrun += sum;

        barrier_raw();                   // reads of Kt(kt) done (no vm drain)
        if (kt < 31) WRITEK();
        barrier_lds();                   // Kt(kt+1) published
    }

    const float cfix = __builtin_amdgcn_logf(lrun);  // log2(l)

    f32x4 cacc[4] = {};

    LOADK(0); LOADV(0);
    WRITEK(); WRITEV();
    __syncthreads();

    // ---- pass 2: recompute, normalize, store attn (NT x4), PV ----
    for (int kt = 0; kt < 32; ++kt) {
        if (kt < 31) { LOADK(kt + 1); LOADV(kt + 1); }

        #pragma unroll
        for (int sub = 0; sub < 4; ++sub) {
            int kr = sub * 16 + ln;
            f16x8 k0 = *(const f16x8*)&Kt[kr * 64 + SWZ(kr, lg * 8)];
            f16x8 k1 = *(const f16x8*)&Kt[kr * 64 + SWZ(kr, 32 + lg * 8)];
            const int kjb = kt * 64 + sub * 16 + lg * 4;
            f16x4 mr = *(const f16x4*)&mrowh[kjb];
            float rp[4], mc[4];
            #pragma unroll
            for (int v = 0; v < 4; ++v) {
                int d = q - (kjb + v); d = d < 0 ? -d : d;
                rp[v] = __builtin_amdgcn_rcpf((float)(SS + d));
                mc[v] = (float)mr[v] - cfix;
            }
            f32x4 sa = {0.f, 0.f, 0.f, 0.f};
            __builtin_amdgcn_s_setprio(1);
            sa = mfma16(k0, aq0, sa);
            sa = mfma16(k1, aq1, sa);
            __builtin_amdgcn_s_setprio(0);
            f32x4 p;
            #pragma unroll
            for (int v = 0; v < 4; ++v)
                p[v] = __builtin_amdgcn_exp2f(sa[v] * SC + mc[v]) * rp[v];
            __builtin_nontemporal_store(
                p, (fvec4*)(attn_out + ((size_t)bh * SS + q) * SS + kjb));
            f16x4 pc;
            #pragma unroll
            for (int v = 0; v < 4; ++v) pc[v] = (f16)p[v];
            const int prow = wv * 16 + ln;
            *(f16x4*)&Ps[prow * 64 + SWZ(prow, sub * 16 + lg * 4)] = pc;
        }
        // PV: A = P (wave-private Ps rows), B = V tile in LDS
        #pragma unroll
        for (int ks = 0; ks < 2; ++ks) {
            const int prow = wv * 16 + ln;
            f16x8 ap = *(const f16x8*)&Ps[prow * 64 + SWZ(prow, ks * 32 + lg * 8)];
            f16x8 bv0 = *(const f16x8*)&Vt[(0 * 16 + ln) * 64 + SWZ(0 * 16 + ln, ks * 32 + lg * 8)];
            f16x8 bv1 = *(const f16x8*)&Vt[(1 * 16 + ln) * 64 + SWZ(1 * 16 + ln, ks * 32 + lg * 8)];
            f16x8 bv2 = *(const f16x8*)&Vt[(2 * 16 + ln) * 64 + SWZ(2 * 16 + ln, ks * 32 + lg * 8)];
            f16x8 bv3 = *(const f16x8*)&Vt[(3 * 16 + ln) * 64 + SWZ(3 * 16 + ln, ks * 32 + lg * 8)];
            __builtin_amdgcn_s_setprio(1);
            cacc[0] = mfma16(ap, bv0, cacc[0]);
            cacc[1] = mfma16(ap, bv1, cacc[1]);
            cacc[2] = mfma16(ap, bv2, cacc[2]);
            cacc[3] = mfma16(ap, bv3, cacc[3]);
            __builtin_amdgcn_s_setprio(0);
        }

        barrier_raw();                   // reads of Kt/Vt(kt) done (no drain)
        if (kt < 31) { WRITEK(); WRITEV(); }
        barrier_lds();                   // tiles (kt+1) published
    }

    #pragma unroll
    for (int nsub = 0; nsub < 4; ++nsub) {
        #pragma unroll
        for (int v = 0; v < 4; ++v) {
            int s = q0 + wv * 16 + lg * 4 + v;
            ctx_out[(size_t)(b * SS + s) * DD + h * DHH + nsub * 16 + ln] = (f16)cacc[nsub][v];
        }
    }
    #undef LOADK
    #undef WRITEK
    #undef LOADV
    #undef WRITEV
}

// ---------------- host launch ----------------
extern "C" void kernel_launch(void* const* d_in, const int* in_sizes, int n_in,
                              void* d_out, int out_size, void* d_ws, size_t ws_size,
                              hipStream_t stream)
{
    const float* query = (const float*)d_in[0];
    const float* key   = (const float*)d_in[1];
    const float* value = (const float*)d_in[2];
    const float* mask  = (const float*)d_in[3];
    const float* pen   = (const float*)d_in[4];
    const float* Wq = (const float*)d_in[6];
    const float* Wk = (const float*)d_in[7];
    const float* Wv = (const float*)d_in[8];
    const float* Wo = (const float*)d_in[9];
    const float* bo = (const float*)d_in[10];

    char* ws = (char*)d_ws;
    f16* Wqt   = (f16*)(ws);
    f16* Wkt   = (f16*)(ws + (2ull << 20));
    f16* Wvt   = (f16*)(ws + (4ull << 20));
    f16* Wot   = (f16*)(ws + (6ull << 20));
    f16* qbuf  = (f16*)(ws + (8ull << 20));
    f16* kbuf  = (f16*)(ws + (16ull << 20));
    f16* vtbuf = (f16*)(ws + (24ull << 20));
    f16* ctx   = (f16*)(ws + (32ull << 20));

    float* out_main = (float*)d_out;
    float* attn_out = (float*)d_out + (size_t)BB * SS * DD;

    wtrans_kernel<<<dim3(16, 16, 4), 256, 0, stream>>>(Wq, Wk, Wv, Wo, Wqt, Wkt, Wvt, Wot);
    gemm_qkv<<<dim3(768), 256, 0, stream>>>(query, key, value, Wqt, Wkt, Wvt, qbuf, kbuf, vtbuf);
    attn_kernel<<<dim3(1024), 256, 0, stream>>>(qbuf, kbuf, vtbuf, mask, pen, attn_out, ctx);
    gemm_out<<<dim3(256), 256, 0, stream>>>(ctx, Wot, bo, out_main);
}

// Round 17
// 275.100 us; speedup vs baseline: 1.0263x; 1.0263x over previous
//
#include <hip/hip_runtime.h>
#include <math.h>

#define BB 2
#define SS 2048
#define DD 1024
#define HH 16
#define DHH 64

typedef _Float16 f16;
typedef f16 f16x8 __attribute__((ext_vector_type(8)));
typedef f16 f16x4 __attribute__((ext_vector_type(4)));
typedef float f32x4 __attribute__((ext_vector_type(4)));
typedef float fvec4 __attribute__((ext_vector_type(4)));

#define LOG2E 1.4426950408889634f

static __device__ __forceinline__ f32x4 mfma16(f16x8 a, f16x8 b, f32x4 c) {
    return __builtin_amdgcn_mfma_f32_16x16x32_f16(a, b, c, 0, 0, 0);
}

// XOR bank swizzle (T2): col in f16 units; toggles byte bits 4..6.
#define SWZ(r, c) ((c) ^ (((r) & 7) << 3))

static __device__ __forceinline__ void gload_lds16(const void* g, void* l) {
    __builtin_amdgcn_global_load_lds(
        (const __attribute__((address_space(1))) void*)g,
        (__attribute__((address_space(3))) void*)l, 16, 0, 0);
}

// Raw barrier: no vmcnt drain (NT stores stay in flight).
static __device__ __forceinline__ void barrier_raw() {
    __builtin_amdgcn_sched_barrier(0);
    __builtin_amdgcn_s_barrier();
    __builtin_amdgcn_sched_barrier(0);
}
// Barrier publishing LDS writes: lgkmcnt(0) only, no vmcnt drain.
static __device__ __forceinline__ void barrier_lds() {
    asm volatile("s_waitcnt lgkmcnt(0)" ::: "memory");
    __builtin_amdgcn_s_barrier();
    __builtin_amdgcn_sched_barrier(0);
}

// ---------------- weight transpose + f32->f16 convert ----------------
__global__ __launch_bounds__(256) void wtrans_kernel(
    const float* __restrict__ w0, const float* __restrict__ w1,
    const float* __restrict__ w2, const float* __restrict__ w3,
    f16* __restrict__ o0, f16* __restrict__ o1,
    f16* __restrict__ o2, f16* __restrict__ o3)
{
    const float* src; f16* dst;
    switch (blockIdx.z) {
        case 0:  src = w0; dst = o0; break;
        case 1:  src = w1; dst = o1; break;
        case 2:  src = w2; dst = o2; break;
        default: src = w3; dst = o3; break;
    }
    __shared__ float t[64][65];
    const int tid = threadIdx.x;
    const int n0 = blockIdx.x * 64, k0 = blockIdx.y * 64;
    const int r = tid >> 4, c4 = (tid & 15) * 4;
    #pragma unroll
    for (int p = 0; p < 4; ++p) {
        int row = r + p * 16;
        fvec4 v = *(const fvec4*)&src[(size_t)(k0 + row) * DD + n0 + c4];
        #pragma unroll
        for (int j = 0; j < 4; ++j) t[row][c4 + j] = v[j];
    }
    __syncthreads();
    #pragma unroll
    for (int p = 0; p < 4; ++p) {
        int row = r + p * 16;  // n-local
        f16x4 v;
        #pragma unroll
        for (int j = 0; j < 4; ++j) v[j] = (f16)t[c4 + j][row];
        *(f16x4*)&dst[(size_t)(n0 + row) * DD + k0 + c4] = v;
    }
}

// ---------------- fused QKV projection GEMM (R7, unchanged) ----------------
__global__ __launch_bounds__(256) void gemm_qkv(
    const float* __restrict__ Aq, const float* __restrict__ Ak, const float* __restrict__ Av,
    const f16* __restrict__ Wqt, const f16* __restrict__ Wkt, const f16* __restrict__ Wvt,
    f16* __restrict__ oq, f16* __restrict__ ok, f16* __restrict__ ovt)
{
    const int K = DD;
    const int l = (blockIdx.x & 7) * 96 + (blockIdx.x >> 3);
    const int z  = (l % 96) / 32;
    const int mt = (l / 96) * 4 + (l % 32) / 8;
    const int nt = l % 8;

    const float* A; const f16* Bt; f16* C;
    switch (z) {
        case 0:  A = Aq; Bt = Wqt; C = oq; break;
        case 1:  A = Ak; Bt = Wkt; C = ok; break;
        default: A = Av; Bt = Wvt; C = ovt; break;
    }
    const int m0 = mt * 128, n0 = nt * 128;
    const int tid = threadIdx.x, lane = tid & 63;
    const int wm = (tid >> 7) & 1, wn = (tid >> 6) & 1;
    const int ln = lane & 15, lg = lane >> 4;

    __shared__ f16 As[128 * 64];
    __shared__ f16 Bs[128 * 64];

    f32x4 acc[4][4] = {};

    const int sr = tid >> 3;
    const int sc = (tid & 7) * 8;
    const int l8 = sr & 7;
    const int bsrc = ((tid & 7) ^ l8) * 8;
    const int ldsbase = (sr & ~7) * 64;

    for (int k0 = 0; k0 < K; k0 += 64) {
        #pragma unroll
        for (int p = 0; p < 4; ++p)
            gload_lds16(Bt + (size_t)(n0 + sr + p * 32) * K + k0 + bsrc,
                        &Bs[ldsbase + p * 32 * 64]);
        #pragma unroll
        for (int p = 0; p < 4; ++p) {
            int row = sr + p * 32;
            const float* s = A + (size_t)(m0 + row) * K + k0 + sc;
            fvec4 x0 = *(const fvec4*)s;
            fvec4 x1 = *(const fvec4*)(s + 4);
            f16x8 v;
            #pragma unroll
            for (int j = 0; j < 4; ++j) { v[j] = (f16)x0[j]; v[j + 4] = (f16)x1[j]; }
            *(f16x8*)&As[row * 64 + SWZ(row, sc)] = v;
        }
        __syncthreads();
        #pragma unroll
        for (int ks = 0; ks < 2; ++ks) {
            f16x8 af[4], bf[4];
            #pragma unroll
            for (int i = 0; i < 4; ++i) {
                int ra = wm * 64 + i * 16 + ln, rb = wn * 64 + i * 16 + ln;
                int cc = ks * 32 + lg * 8;
                af[i] = *(const f16x8*)&As[ra * 64 + SWZ(ra, cc)];
                bf[i] = *(const f16x8*)&Bs[rb * 64 + SWZ(rb, cc)];
            }
            __builtin_amdgcn_s_setprio(1);
            #pragma unroll
            for (int i = 0; i < 4; ++i)
                #pragma unroll
                for (int j = 0; j < 4; ++j)
                    acc[i][j] = mfma16(af[i], bf[j], acc[i][j]);
            __builtin_amdgcn_s_setprio(0);
        }
        __syncthreads();
    }

    const int vmode = (z == 2);
    #pragma unroll
    for (int i = 0; i < 4; ++i) {
        #pragma unroll
        for (int j = 0; j < 4; ++j) {
            if (vmode) {
                int m = m0 + wm * 64 + i * 16 + lg * 4;
                int n = n0 + wn * 64 + j * 16 + ln;
                int b = m >> 11, s = m & (SS - 1);
                int h = n >> 6, dh = n & 63;
                f16x4 v4;
                #pragma unroll
                for (int v = 0; v < 4; ++v) v4[v] = (f16)acc[i][j][v];
                *(f16x4*)&C[((size_t)((b * HH + h) * DHH + dh)) * SS + s] = v4;
            } else {
                #pragma unroll
                for (int v = 0; v < 4; ++v) {
                    int m = m0 + wm * 64 + i * 16 + lg * 4 + v;
                    int n = n0 + wn * 64 + j * 16 + ln;
                    int b = m >> 11, s = m & (SS - 1);
                    int h = n >> 6, dh = n & 63;
                    C[((size_t)((b * HH + h) * SS + s)) * DHH + dh] = (f16)acc[i][j][v];
                }
            }
        }
    }
}

// ---------------- final projection GEMM (R7, unchanged) ----------------
__global__ __launch_bounds__(256) void gemm_out(
    const f16* __restrict__ A, const f16* __restrict__ Bt,
    const float* __restrict__ bias, float* __restrict__ C)
{
    const int K = DD;
    const int l = (blockIdx.x & 7) * 32 + (blockIdx.x >> 3);
    const int mt = (l / 32) * 4 + (l % 32) / 8;
    const int nt = l % 8;
    const int m0 = mt * 128, n0 = nt * 128;
    const int tid = threadIdx.x, lane = tid & 63;
    const int wm = (tid >> 7) & 1, wn = (tid >> 6) & 1;
    const int ln = lane & 15, lg = lane >> 4;

    __shared__ f16 As[128 * 64];
    __shared__ f16 Bs[128 * 64];

    f32x4 acc[4][4] = {};

    const int sr = tid >> 3;
    const int l8 = sr & 7;
    const int bsrc = ((tid & 7) ^ l8) * 8;
    const int ldsbase = (sr & ~7) * 64;

    for (int k0 = 0; k0 < K; k0 += 64) {
        #pragma unroll
        for (int p = 0; p < 4; ++p) {
            gload_lds16(A + (size_t)(m0 + sr + p * 32) * K + k0 + bsrc,
                        &As[ldsbase + p * 32 * 64]);
            gload_lds16(Bt + (size_t)(n0 + sr + p * 32) * K + k0 + bsrc,
                        &Bs[ldsbase + p * 32 * 64]);
        }
        __syncthreads();
        #pragma unroll
        for (int ks = 0; ks < 2; ++ks) {
            f16x8 af[4], bf[4];
            #pragma unroll
            for (int i = 0; i < 4; ++i) {
                int ra = wm * 64 + i * 16 + ln, rb = wn * 64 + i * 16 + ln;
                int cc = ks * 32 + lg * 8;
                af[i] = *(const f16x8*)&As[ra * 64 + SWZ(ra, cc)];
                bf[i] = *(const f16x8*)&Bs[rb * 64 + SWZ(rb, cc)];
            }
            __builtin_amdgcn_s_setprio(1);
            #pragma unroll
            for (int i = 0; i < 4; ++i)
                #pragma unroll
                for (int j = 0; j < 4; ++j)
                    acc[i][j] = mfma16(af[i], bf[j], acc[i][j]);
            __builtin_amdgcn_s_setprio(0);
        }
        __syncthreads();
    }

    #pragma unroll
    for (int i = 0; i < 4; ++i)
        #pragma unroll
        for (int j = 0; j < 4; ++j)
            #pragma unroll
            for (int v = 0; v < 4; ++v) {
                int m = m0 + wm * 64 + i * 16 + lg * 4 + v;
                int n = n0 + wn * 64 + j * 16 + ln;
                C[(size_t)m * DD + n] = acc[i][j][v] + bias[n];
            }
}

// ---------------- fused attention (R16 base, 2q x 2k wave split) -----------
// Minimal diff vs R16: wave roles change from 4x(16q, all k) to
// (wq,wk) = 2 q-halves x 2 k-halves. Each wave: 32 q (aq reused across its
// 2 q-groups) x 32 k (own half of each 64-k tile). Per-iter LDS frag reads
// drop 18 -> 10 b128 (QK 4 + ap 2 + bv 4); MFMA/exp/store counts identical;
// same tiles, staging, barriers, grid, LDS (28 KB). One-time combines:
// l across k-halves (128 B), ctx across k-halves (16 KB overlay on Kt/Vt).
__global__ __launch_bounds__(256, 4) void attn_kernel(
    const f16* __restrict__ qg, const f16* __restrict__ kg, const f16* __restrict__ vtg,
    const float* __restrict__ maskg, const float* __restrict__ peng,
    float* __restrict__ attn_out, f16* __restrict__ ctx_out)
{
    const int bid = blockIdx.x;
    const int wg = (bid & 7) * 128 + (bid >> 3);   // bijective XCD swizzle
    const int bh = wg >> 5;                        // 0..31
    const int b = bh >> 4, h = bh & 15;
    const int q0 = (wg & 31) * 64;

    const int tid = threadIdx.x, lane = tid & 63;
    const int wq = tid >> 7, wk = (tid >> 6) & 1;  // q-half, k-half
    const int ln = lane & 15, lg = lane >> 4;

    __shared__ f16 arena[12288];      // 24 KB: Kt 8K | Vt 8K | Ps 8K
    __shared__ f16 mrowh[SS];         // 4 KB  mask * (-1e9*log2e)
    f16* const Kt = arena;
    f16* const Vt = arena + 4096;
    f16* const Ps = arena + 8192;

    for (int i = tid; i < SS; i += 256)
        mrowh[i] = (f16)fmaxf(maskg[b * SS + i] * (-1e9f * LOG2E), -60000.f);

    // Q fragments for this wave's two 16-q groups
    f16x8 aq0[2], aq1[2];
    #pragma unroll
    for (int g = 0; g < 2; ++g) {
        const f16* qb = qg + ((size_t)bh * SS + q0 + wq * 32 + g * 16 + ln) * DHH;
        aq0[g] = *(const f16x8*)(qb + lg * 8);
        aq1[g] = *(const f16x8*)(qb + 32 + lg * 8);
    }

    const f16* kbase = kg + (size_t)bh * SS * DHH;
    const f16* vbase = vtg + (size_t)bh * DHH * SS;

    // reg staging (unchanged from R10/R16): 2 chunks/thread each for K and V
    const int krow = tid >> 3, kcol = (tid & 7) * 8;
    f16x8 kst0, kst1, vst0, vst1;

    #define LOADK(kt) { kst0 = *(const f16x8*)(kbase + ((size_t)(kt) * 64 + krow) * DHH + kcol); \
                        kst1 = *(const f16x8*)(kbase + ((size_t)(kt) * 64 + krow + 32) * DHH + kcol); }
    #define WRITEK()  { *(f16x8*)&Kt[krow * 64 + SWZ(krow, kcol)] = kst0; \
                        *(f16x8*)&Kt[(krow + 32) * 64 + SWZ(krow + 32, kcol)] = kst1; }
    #define LOADV(kt) { vst0 = *(const f16x8*)(vbase + (size_t)krow * SS + (kt) * 64 + kcol); \
                        vst1 = *(const f16x8*)(vbase + (size_t)(krow + 32) * SS + (kt) * 64 + kcol); }
    #define WRITEV()  { *(f16x8*)&Vt[krow * 64 + SWZ(krow, kcol)] = vst0; \
                        *(f16x8*)&Vt[(krow + 32) * 64 + SWZ(krow + 32, kcol)] = vst1; }

    const float SC = 0.125f * LOG2E;

    LOADK(0);
    WRITEK();
    __syncthreads();

    float lsum[2] = {0.f, 0.f};

    // ---- pass 1: partial l over own k-half; shfl reduction hoisted ----
    for (int kt = 0; kt < 32; ++kt) {
        if (kt < 31) LOADK(kt + 1);

        #pragma unroll
        for (int ksub = 0; ksub < 2; ++ksub) {
            const int sub = wk * 2 + ksub;
            const int kr = sub * 16 + ln;
            f16x8 k0 = *(const f16x8*)&Kt[kr * 64 + SWZ(kr, lg * 8)];
            f16x8 k1 = *(const f16x8*)&Kt[kr * 64 + SWZ(kr, 32 + lg * 8)];
            const int kjb = kt * 64 + sub * 16 + lg * 4;
            f16x4 mr = *(const f16x4*)&mrowh[kjb];
            #pragma unroll
            for (int g = 0; g < 2; ++g) {
                f32x4 sa = {0.f, 0.f, 0.f, 0.f};
                __builtin_amdgcn_s_setprio(1);
                sa = mfma16(k0, aq0[g], sa);
                sa = mfma16(k1, aq1[g], sa);
                __builtin_amdgcn_s_setprio(0);
                const int qq = q0 + wq * 32 + g * 16 + ln;
                #pragma unroll
                for (int v = 0; v < 4; ++v) {
                    int d = qq - (kjb + v); d = d < 0 ? -d : d;
                    lsum[g] += __builtin_amdgcn_exp2f(sa[v] * SC + (float)mr[v])
                             * __builtin_amdgcn_rcpf((float)(SS + d));
                }
            }
        }
        barrier_raw();                   // reads of Kt(kt) done (no vm drain)
        if (kt < 31) WRITEK();
        barrier_lds();                   // Kt(kt+1) published
    }

    // reduce over lg in-wave, then combine the two k-halves via LDS
    float cfix[2];
    {
        #pragma unroll
        for (int g = 0; g < 2; ++g) {
            lsum[g] += __shfl_xor(lsum[g], 16);
            lsum[g] += __shfl_xor(lsum[g], 32);
        }
        float* lred = (float*)Ps;        // 128 floats
        if (lg == 0) {
            lred[wk * 64 + wq * 32 + ln]      = lsum[0];
            lred[wk * 64 + wq * 32 + 16 + ln] = lsum[1];
        }
        __syncthreads();
        #pragma unroll
        for (int g = 0; g < 2; ++g)
            cfix[g] = __builtin_amdgcn_logf(
                lred[wq * 32 + g * 16 + ln] + lred[64 + wq * 32 + g * 16 + ln]);
        __syncthreads();
    }

    f32x4 cacc[2][4] = {};

    LOADK(0); LOADV(0);
    WRITEK(); WRITEV();
    __syncthreads();

    // ---- pass 2: recompute, store attn (NT x4), PV on own k-half ----
    for (int kt = 0; kt < 32; ++kt) {
        if (kt < 31) { LOADK(kt + 1); LOADV(kt + 1); }

        #pragma unroll
        for (int ksub = 0; ksub < 2; ++ksub) {
            const int sub = wk * 2 + ksub;
            const int kr = sub * 16 + ln;
            f16x8 k0 = *(const f16x8*)&Kt[kr * 64 + SWZ(kr, lg * 8)];
            f16x8 k1 = *(const f16x8*)&Kt[kr * 64 + SWZ(kr, 32 + lg * 8)];
            const int kjb = kt * 64 + sub * 16 + lg * 4;
            f16x4 mr = *(const f16x4*)&mrowh[kjb];
            #pragma unroll
            for (int g = 0; g < 2; ++g) {
                f32x4 sa = {0.f, 0.f, 0.f, 0.f};
                __builtin_amdgcn_s_setprio(1);
                sa = mfma16(k0, aq0[g], sa);
                sa = mfma16(k1, aq1[g], sa);
                __builtin_amdgcn_s_setprio(0);
                const int qq = q0 + wq * 32 + g * 16 + ln;
                f32x4 p;
                #pragma unroll
                for (int v = 0; v < 4; ++v) {
                    int d = qq - (kjb + v); d = d < 0 ? -d : d;
                    p[v] = __builtin_amdgcn_exp2f(sa[v] * SC + (float)mr[v] - cfix[g])
                         * __builtin_amdgcn_rcpf((float)(SS + d));
                }
                __builtin_nontemporal_store(
                    p, (fvec4*)(attn_out + ((size_t)bh * SS + qq) * SS + kjb));
                f16x4 pc;
                #pragma unroll
                for (int v = 0; v < 4; ++v) pc[v] = (f16)p[v];
                const int prow = wq * 32 + g * 16 + ln;
                *(f16x4*)&Ps[prow * 64 + SWZ(prow, sub * 16 + lg * 4)] = pc;
            }
        }
        // PV on own 32-k half (ks = wk); bv shared across the 2 q-groups
        {
            f16x8 bv[4];
            #pragma unroll
            for (int nsub = 0; nsub < 4; ++nsub) {
                int vr = nsub * 16 + ln;
                bv[nsub] = *(const f16x8*)&Vt[vr * 64 + SWZ(vr, wk * 32 + lg * 8)];
            }
            #pragma unroll
            for (int g = 0; g < 2; ++g) {
                const int prow = wq * 32 + g * 16 + ln;
                f16x8 ap = *(const f16x8*)&Ps[prow * 64 + SWZ(prow, wk * 32 + lg * 8)];
                __builtin_amdgcn_s_setprio(1);
                #pragma unroll
                for (int nsub = 0; nsub < 4; ++nsub)
                    cacc[g][nsub] = mfma16(ap, bv[nsub], cacc[g][nsub]);
                __builtin_amdgcn_s_setprio(0);
            }
        }

        barrier_raw();                   // reads of Kt/Vt(kt) done (no drain)
        if (kt < 31) { LOADK(kt + 1); WRITEK(); WRITEV(); }
        barrier_lds();                   // tiles (kt+1) published
    }

    // ---- final cross-k-half ctx combine (16 KB overlay on Kt/Vt) ----
    __syncthreads();
    float* red = (float*)arena;          // [64 q][64 dh] f32 = 16 KB
    if (wk == 1) {
        #pragma unroll
        for (int g = 0; g < 2; ++g)
            #pragma unroll
            for (int nsub = 0; nsub < 4; ++nsub)
                #pragma unroll
                for (int v = 0; v < 4; ++v)
                    red[(wq * 32 + g * 16 + lg * 4 + v) * 64 + nsub * 16 + ln] =
                        cacc[g][nsub][v];
    }
    __syncthreads();
    if (wk == 0) {
        #pragma unroll
        for (int g = 0; g < 2; ++g)
            #pragma unroll
            for (int nsub = 0; nsub < 4; ++nsub)
                #pragma unroll
                for (int v = 0; v < 4; ++v) {
                    float s = cacc[g][nsub][v]
                            + red[(wq * 32 + g * 16 + lg * 4 + v) * 64 + nsub * 16 + ln];
                    int sq = q0 + wq * 32 + g * 16 + lg * 4 + v;
                    ctx_out[(size_t)(b * SS + sq) * DD + h * DHH + nsub * 16 + ln] = (f16)s;
                }
    }
    #undef LOADK
    #undef WRITEK
    #undef LOADV
    #undef WRITEV
}

// ---------------- host launch ----------------
extern "C" void kernel_launch(void* const* d_in, const int* in_sizes, int n_in,
                              void* d_out, int out_size, void* d_ws, size_t ws_size,
                              hipStream_t stream)
{
    const float* query = (const float*)d_in[0];
    const float* key   = (const float*)d_in[1];
    const float* value = (const float*)d_in[2];
    const float* mask  = (const float*)d_in[3];
    const float* pen   = (const float*)d_in[4];
    const float* Wq = (const float*)d_in[6];
    const float* Wk = (const float*)d_in[7];
    const float* Wv = (const float*)d_in[8];
    const float* Wo = (const float*)d_in[9];
    const float* bo = (const float*)d_in[10];

    char* ws = (char*)d_ws;
    f16* Wqt   = (f16*)(ws);
    f16* Wkt   = (f16*)(ws + (2ull << 20));
    f16* Wvt   = (f16*)(ws + (4ull << 20));
    f16* Wot   = (f16*)(ws + (6ull << 20));
    f16* qbuf  = (f16*)(ws + (8ull << 20));
    f16* kbuf  = (f16*)(ws + (16ull << 20));
    f16* vtbuf = (f16*)(ws + (24ull << 20));
    f16* ctx   = (f16*)(ws + (32ull << 20));

    float* out_main = (float*)d_out;
    float* attn_out = (float*)d_out + (size_t)BB * SS * DD;

    wtrans_kernel<<<dim3(16, 16, 4), 256, 0, stream>>>(Wq, Wk, Wv, Wo, Wqt, Wkt, Wvt, Wot);
    gemm_qkv<<<dim3(768), 256, 0, stream>>>(query, key, value, Wqt, Wkt, Wvt, qbuf, kbuf, vtbuf);
    attn_kernel<<<dim3(1024), 256, 0, stream>>>(qbuf, kbuf, vtbuf, mask, pen, attn_out, ctx);
    gemm_out<<<dim3(256), 256, 0, stream>>>(ctx, Wot, bo, out_main);
}

// Round 18
// 264.744 us; speedup vs baseline: 1.0665x; 1.0391x over previous
//
#include <hip/hip_runtime.h>
#include <math.h>

#define BB 2
#define SS 2048
#define DD 1024
#define HH 16
#define DHH 64

typedef _Float16 f16;
typedef f16 f16x8 __attribute__((ext_vector_type(8)));
typedef f16 f16x4 __attribute__((ext_vector_type(4)));
typedef float f32x4 __attribute__((ext_vector_type(4)));
typedef float fvec4 __attribute__((ext_vector_type(4)));

#define LOG2E 1.4426950408889634f

static __device__ __forceinline__ f32x4 mfma16(f16x8 a, f16x8 b, f32x4 c) {
    return __builtin_amdgcn_mfma_f32_16x16x32_f16(a, b, c, 0, 0, 0);
}

// XOR bank swizzle (T2): col in f16 units; toggles byte bits 4..6.
#define SWZ(r, c) ((c) ^ (((r) & 7) << 3))

static __device__ __forceinline__ void gload_lds16(const void* g, void* l) {
    __builtin_amdgcn_global_load_lds(
        (const __attribute__((address_space(1))) void*)g,
        (__attribute__((address_space(3))) void*)l, 16, 0, 0);
}

// Raw barrier: no vmcnt drain (NT stores stay in flight).
static __device__ __forceinline__ void barrier_raw() {
    __builtin_amdgcn_sched_barrier(0);
    __builtin_amdgcn_s_barrier();
    __builtin_amdgcn_sched_barrier(0);
}
// Barrier publishing LDS writes: lgkmcnt(0) only, no vmcnt drain.
static __device__ __forceinline__ void barrier_lds() {
    asm volatile("s_waitcnt lgkmcnt(0)" ::: "memory");
    __builtin_amdgcn_s_barrier();
    __builtin_amdgcn_sched_barrier(0);
}

// ---------------- weight transpose + f32->f16 convert ----------------
__global__ __launch_bounds__(256) void wtrans_kernel(
    const float* __restrict__ w0, const float* __restrict__ w1,
    const float* __restrict__ w2, const float* __restrict__ w3,
    f16* __restrict__ o0, f16* __restrict__ o1,
    f16* __restrict__ o2, f16* __restrict__ o3)
{
    const float* src; f16* dst;
    switch (blockIdx.z) {
        case 0:  src = w0; dst = o0; break;
        case 1:  src = w1; dst = o1; break;
        case 2:  src = w2; dst = o2; break;
        default: src = w3; dst = o3; break;
    }
    __shared__ float t[64][65];
    const int tid = threadIdx.x;
    const int n0 = blockIdx.x * 64, k0 = blockIdx.y * 64;
    const int r = tid >> 4, c4 = (tid & 15) * 4;
    #pragma unroll
    for (int p = 0; p < 4; ++p) {
        int row = r + p * 16;
        fvec4 v = *(const fvec4*)&src[(size_t)(k0 + row) * DD + n0 + c4];
        #pragma unroll
        for (int j = 0; j < 4; ++j) t[row][c4 + j] = v[j];
    }
    __syncthreads();
    #pragma unroll
    for (int p = 0; p < 4; ++p) {
        int row = r + p * 16;  // n-local
        f16x4 v;
        #pragma unroll
        for (int j = 0; j < 4; ++j) v[j] = (f16)t[c4 + j][row];
        *(f16x4*)&dst[(size_t)(n0 + row) * DD + k0 + c4] = v;
    }
}

// ---------------- fused QKV projection GEMM (R7, unchanged) ----------------
__global__ __launch_bounds__(256) void gemm_qkv(
    const float* __restrict__ Aq, const float* __restrict__ Ak, const float* __restrict__ Av,
    const f16* __restrict__ Wqt, const f16* __restrict__ Wkt, const f16* __restrict__ Wvt,
    f16* __restrict__ oq, f16* __restrict__ ok, f16* __restrict__ ovt)
{
    const int K = DD;
    const int l = (blockIdx.x & 7) * 96 + (blockIdx.x >> 3);
    const int z  = (l % 96) / 32;
    const int mt = (l / 96) * 4 + (l % 32) / 8;
    const int nt = l % 8;

    const float* A; const f16* Bt; f16* C;
    switch (z) {
        case 0:  A = Aq; Bt = Wqt; C = oq; break;
        case 1:  A = Ak; Bt = Wkt; C = ok; break;
        default: A = Av; Bt = Wvt; C = ovt; break;
    }
    const int m0 = mt * 128, n0 = nt * 128;
    const int tid = threadIdx.x, lane = tid & 63;
    const int wm = (tid >> 7) & 1, wn = (tid >> 6) & 1;
    const int ln = lane & 15, lg = lane >> 4;

    __shared__ f16 As[128 * 64];
    __shared__ f16 Bs[128 * 64];

    f32x4 acc[4][4] = {};

    const int sr = tid >> 3;
    const int sc = (tid & 7) * 8;
    const int l8 = sr & 7;
    const int bsrc = ((tid & 7) ^ l8) * 8;
    const int ldsbase = (sr & ~7) * 64;

    for (int k0 = 0; k0 < K; k0 += 64) {
        #pragma unroll
        for (int p = 0; p < 4; ++p)
            gload_lds16(Bt + (size_t)(n0 + sr + p * 32) * K + k0 + bsrc,
                        &Bs[ldsbase + p * 32 * 64]);
        #pragma unroll
        for (int p = 0; p < 4; ++p) {
            int row = sr + p * 32;
            const float* s = A + (size_t)(m0 + row) * K + k0 + sc;
            fvec4 x0 = *(const fvec4*)s;
            fvec4 x1 = *(const fvec4*)(s + 4);
            f16x8 v;
            #pragma unroll
            for (int j = 0; j < 4; ++j) { v[j] = (f16)x0[j]; v[j + 4] = (f16)x1[j]; }
            *(f16x8*)&As[row * 64 + SWZ(row, sc)] = v;
        }
        __syncthreads();
        #pragma unroll
        for (int ks = 0; ks < 2; ++ks) {
            f16x8 af[4], bf[4];
            #pragma unroll
            for (int i = 0; i < 4; ++i) {
                int ra = wm * 64 + i * 16 + ln, rb = wn * 64 + i * 16 + ln;
                int cc = ks * 32 + lg * 8;
                af[i] = *(const f16x8*)&As[ra * 64 + SWZ(ra, cc)];
                bf[i] = *(const f16x8*)&Bs[rb * 64 + SWZ(rb, cc)];
            }
            __builtin_amdgcn_s_setprio(1);
            #pragma unroll
            for (int i = 0; i < 4; ++i)
                #pragma unroll
                for (int j = 0; j < 4; ++j)
                    acc[i][j] = mfma16(af[i], bf[j], acc[i][j]);
            __builtin_amdgcn_s_setprio(0);
        }
        __syncthreads();
    }

    const int vmode = (z == 2);
    #pragma unroll
    for (int i = 0; i < 4; ++i) {
        #pragma unroll
        for (int j = 0; j < 4; ++j) {
            if (vmode) {
                int m = m0 + wm * 64 + i * 16 + lg * 4;
                int n = n0 + wn * 64 + j * 16 + ln;
                int b = m >> 11, s = m & (SS - 1);
                int h = n >> 6, dh = n & 63;
                f16x4 v4;
                #pragma unroll
                for (int v = 0; v < 4; ++v) v4[v] = (f16)acc[i][j][v];
                *(f16x4*)&C[((size_t)((b * HH + h) * DHH + dh)) * SS + s] = v4;
            } else {
                #pragma unroll
                for (int v = 0; v < 4; ++v) {
                    int m = m0 + wm * 64 + i * 16 + lg * 4 + v;
                    int n = n0 + wn * 64 + j * 16 + ln;
                    int b = m >> 11, s = m & (SS - 1);
                    int h = n >> 6, dh = n & 63;
                    C[((size_t)((b * HH + h) * SS + s)) * DHH + dh] = (f16)acc[i][j][v];
                }
            }
        }
    }
}

// ---------------- final projection GEMM (R7, unchanged) ----------------
__global__ __launch_bounds__(256) void gemm_out(
    const f16* __restrict__ A, const f16* __restrict__ Bt,
    const float* __restrict__ bias, float* __restrict__ C)
{
    const int K = DD;
    const int l = (blockIdx.x & 7) * 32 + (blockIdx.x >> 3);
    const int mt = (l / 32) * 4 + (l % 32) / 8;
    const int nt = l % 8;
    const int m0 = mt * 128, n0 = nt * 128;
    const int tid = threadIdx.x, lane = tid & 63;
    const int wm = (tid >> 7) & 1, wn = (tid >> 6) & 1;
    const int ln = lane & 15, lg = lane >> 4;

    __shared__ f16 As[128 * 64];
    __shared__ f16 Bs[128 * 64];

    f32x4 acc[4][4] = {};

    const int sr = tid >> 3;
    const int l8 = sr & 7;
    const int bsrc = ((tid & 7) ^ l8) * 8;
    const int ldsbase = (sr & ~7) * 64;

    for (int k0 = 0; k0 < K; k0 += 64) {
        #pragma unroll
        for (int p = 0; p < 4; ++p) {
            gload_lds16(A + (size_t)(m0 + sr + p * 32) * K + k0 + bsrc,
                        &As[ldsbase + p * 32 * 64]);
            gload_lds16(Bt + (size_t)(n0 + sr + p * 32) * K + k0 + bsrc,
                        &Bs[ldsbase + p * 32 * 64]);
        }
        __syncthreads();
        #pragma unroll
        for (int ks = 0; ks < 2; ++ks) {
            f16x8 af[4], bf[4];
            #pragma unroll
            for (int i = 0; i < 4; ++i) {
                int ra = wm * 64 + i * 16 + ln, rb = wn * 64 + i * 16 + ln;
                int cc = ks * 32 + lg * 8;
                af[i] = *(const f16x8*)&As[ra * 64 + SWZ(ra, cc)];
                bf[i] = *(const f16x8*)&Bs[rb * 64 + SWZ(rb, cc)];
            }
            __builtin_amdgcn_s_setprio(1);
            #pragma unroll
            for (int i = 0; i < 4; ++i)
                #pragma unroll
                for (int j = 0; j < 4; ++j)
                    acc[i][j] = mfma16(af[i], bf[j], acc[i][j]);
            __builtin_amdgcn_s_setprio(0);
        }
        __syncthreads();
    }

    #pragma unroll
    for (int i = 0; i < 4; ++i)
        #pragma unroll
        for (int j = 0; j < 4; ++j)
            #pragma unroll
            for (int v = 0; v < 4; ++v) {
                int m = m0 + wm * 64 + i * 16 + lg * 4 + v;
                int n = n0 + wn * 64 + j * 16 + ln;
                C[(size_t)m * DD + n] = acc[i][j][v] + bias[n];
            }
}

// ---------------- fused attention (R17 + LOADK fix + 4-way pass-1 split) ---
// Pass 1: 4 waves each own a 16-k slice (sub = wv) of every 64-k tile and
// compute ALL 64 q (4 q-groups in registers) -> 2 b128 frag reads/iter/wave.
// l combined across waves via 1 KB LDS reduce.
// Pass 2: R17's 2q x 2k split, with the duplicate LOADK removed (WRITEK now
// uses the iteration-old load, not a just-issued one).
__global__ __launch_bounds__(256, 4) void attn_kernel(
    const f16* __restrict__ qg, const f16* __restrict__ kg, const f16* __restrict__ vtg,
    const float* __restrict__ maskg, const float* __restrict__ peng,
    float* __restrict__ attn_out, f16* __restrict__ ctx_out)
{
    const int bid = blockIdx.x;
    const int wg = (bid & 7) * 128 + (bid >> 3);   // bijective XCD swizzle
    const int bh = wg >> 5;                        // 0..31
    const int b = bh >> 4, h = bh & 15;
    const int q0 = (wg & 31) * 64;

    const int tid = threadIdx.x, lane = tid & 63;
    const int wv = tid >> 6;                       // wave id (pass-1 k-slice)
    const int wq = tid >> 7, wk = (tid >> 6) & 1;  // pass-2 q-half, k-half
    const int ln = lane & 15, lg = lane >> 4;

    __shared__ f16 arena[12288];      // 24 KB: Kt 8K | Vt 8K | Ps 8K
    __shared__ f16 mrowh[SS];         // 4 KB  mask * (-1e9*log2e)
    f16* const Kt = arena;
    f16* const Vt = arena + 4096;
    f16* const Ps = arena + 8192;

    for (int i = tid; i < SS; i += 256)
        mrowh[i] = (f16)fmaxf(maskg[b * SS + i] * (-1e9f * LOG2E), -60000.f);

    // Q fragments for ALL 4 q-groups (gq = 0..3: q = q0 + gq*16 + ln).
    // Pass 2 uses aq*[wq*2+g].
    f16x8 aq0[4], aq1[4];
    #pragma unroll
    for (int gq = 0; gq < 4; ++gq) {
        const f16* qb = qg + ((size_t)bh * SS + q0 + gq * 16 + ln) * DHH;
        aq0[gq] = *(const f16x8*)(qb + lg * 8);
        aq1[gq] = *(const f16x8*)(qb + 32 + lg * 8);
    }

    const f16* kbase = kg + (size_t)bh * SS * DHH;
    const f16* vbase = vtg + (size_t)bh * DHH * SS;

    // reg staging (unchanged): 2 chunks/thread each for K and V
    const int krow = tid >> 3, kcol = (tid & 7) * 8;
    f16x8 kst0, kst1, vst0, vst1;

    #define LOADK(kt) { kst0 = *(const f16x8*)(kbase + ((size_t)(kt) * 64 + krow) * DHH + kcol); \
                        kst1 = *(const f16x8*)(kbase + ((size_t)(kt) * 64 + krow + 32) * DHH + kcol); }
    #define WRITEK()  { *(f16x8*)&Kt[krow * 64 + SWZ(krow, kcol)] = kst0; \
                        *(f16x8*)&Kt[(krow + 32) * 64 + SWZ(krow + 32, kcol)] = kst1; }
    #define LOADV(kt) { vst0 = *(const f16x8*)(vbase + (size_t)krow * SS + (kt) * 64 + kcol); \
                        vst1 = *(const f16x8*)(vbase + (size_t)(krow + 32) * SS + (kt) * 64 + kcol); }
    #define WRITEV()  { *(f16x8*)&Vt[krow * 64 + SWZ(krow, kcol)] = vst0; \
                        *(f16x8*)&Vt[(krow + 32) * 64 + SWZ(krow + 32, kcol)] = vst1; }

    const float SC = 0.125f * LOG2E;

    LOADK(0);
    WRITEK();
    __syncthreads();

    float lsum[4] = {0.f, 0.f, 0.f, 0.f};

    // ---- pass 1: wave wv owns k-slice sub=wv; computes all 64 q ----
    for (int kt = 0; kt < 32; ++kt) {
        if (kt < 31) LOADK(kt + 1);

        {
            const int kr = wv * 16 + ln;
            f16x8 k0 = *(const f16x8*)&Kt[kr * 64 + SWZ(kr, lg * 8)];
            f16x8 k1 = *(const f16x8*)&Kt[kr * 64 + SWZ(kr, 32 + lg * 8)];
            const int kjb = kt * 64 + wv * 16 + lg * 4;
            f16x4 mr = *(const f16x4*)&mrowh[kjb];
            #pragma unroll
            for (int gq = 0; gq < 4; ++gq) {
                f32x4 sa = {0.f, 0.f, 0.f, 0.f};
                __builtin_amdgcn_s_setprio(1);
                sa = mfma16(k0, aq0[gq], sa);
                sa = mfma16(k1, aq1[gq], sa);
                __builtin_amdgcn_s_setprio(0);
                const int qq = q0 + gq * 16 + ln;
                #pragma unroll
                for (int v = 0; v < 4; ++v) {
                    int d = qq - (kjb + v); d = d < 0 ? -d : d;
                    lsum[gq] += __builtin_amdgcn_exp2f(sa[v] * SC + (float)mr[v])
                              * __builtin_amdgcn_rcpf((float)(SS + d));
                }
            }
        }
        barrier_raw();                   // reads of Kt(kt) done (no vm drain)
        if (kt < 31) WRITEK();
        barrier_lds();                   // Kt(kt+1) published
    }

    // reduce over lg in-wave, then combine the 4 wave k-slices via LDS
    float cfix[2];
    {
        #pragma unroll
        for (int gq = 0; gq < 4; ++gq) {
            lsum[gq] += __shfl_xor(lsum[gq], 16);
            lsum[gq] += __shfl_xor(lsum[gq], 32);
        }
        float* lred = (float*)Ps;        // 4 waves x 64 q = 256 floats (1 KB)
        if (lg == 0) {
            #pragma unroll
            for (int gq = 0; gq < 4; ++gq)
                lred[wv * 64 + gq * 16 + ln] = lsum[gq];
        }
        __syncthreads();
        #pragma unroll
        for (int g = 0; g < 2; ++g) {
            const int gq = wq * 2 + g;
            cfix[g] = __builtin_amdgcn_logf(
                lred[gq * 16 + ln] + lred[64 + gq * 16 + ln]
              + lred[128 + gq * 16 + ln] + lred[192 + gq * 16 + ln]);
        }
        __syncthreads();
    }

    f32x4 cacc[2][4] = {};

    LOADK(0); LOADV(0);
    WRITEK(); WRITEV();
    __syncthreads();

    // ---- pass 2: 2q x 2k split; recompute, store attn (NT x4), PV ----
    for (int kt = 0; kt < 32; ++kt) {
        if (kt < 31) { LOADK(kt + 1); LOADV(kt + 1); }

        #pragma unroll
        for (int ksub = 0; ksub < 2; ++ksub) {
            const int sub = wk * 2 + ksub;
            const int kr = sub * 16 + ln;
            f16x8 k0 = *(const f16x8*)&Kt[kr * 64 + SWZ(kr, lg * 8)];
            f16x8 k1 = *(const f16x8*)&Kt[kr * 64 + SWZ(kr, 32 + lg * 8)];
            const int kjb = kt * 64 + sub * 16 + lg * 4;
            f16x4 mr = *(const f16x4*)&mrowh[kjb];
            #pragma unroll
            for (int g = 0; g < 2; ++g) {
                f32x4 sa = {0.f, 0.f, 0.f, 0.f};
                __builtin_amdgcn_s_setprio(1);
                sa = mfma16(k0, aq0[wq * 2 + g], sa);
                sa = mfma16(k1, aq1[wq * 2 + g], sa);
                __builtin_amdgcn_s_setprio(0);
                const int qq = q0 + wq * 32 + g * 16 + ln;
                f32x4 p;
                #pragma unroll
                for (int v = 0; v < 4; ++v) {
                    int d = qq - (kjb + v); d = d < 0 ? -d : d;
                    p[v] = __builtin_amdgcn_exp2f(sa[v] * SC + (float)mr[v] - cfix[g])
                         * __builtin_amdgcn_rcpf((float)(SS + d));
                }
                __builtin_nontemporal_store(
                    p, (fvec4*)(attn_out + ((size_t)bh * SS + qq) * SS + kjb));
                f16x4 pc;
                #pragma unroll
                for (int v = 0; v < 4; ++v) pc[v] = (f16)p[v];
                const int prow = wq * 32 + g * 16 + ln;
                *(f16x4*)&Ps[prow * 64 + SWZ(prow, sub * 16 + lg * 4)] = pc;
            }
        }
        // PV on own 32-k half (ks = wk); bv shared across the 2 q-groups
        {
            f16x8 bv[4];
            #pragma unroll
            for (int nsub = 0; nsub < 4; ++nsub) {
                int vr = nsub * 16 + ln;
                bv[nsub] = *(const f16x8*)&Vt[vr * 64 + SWZ(vr, wk * 32 + lg * 8)];
            }
            #pragma unroll
            for (int g = 0; g < 2; ++g) {
                const int prow = wq * 32 + g * 16 + ln;
                f16x8 ap = *(const f16x8*)&Ps[prow * 64 + SWZ(prow, wk * 32 + lg * 8)];
                __builtin_amdgcn_s_setprio(1);
                #pragma unroll
                for (int nsub = 0; nsub < 4; ++nsub)
                    cacc[g][nsub] = mfma16(ap, bv[nsub], cacc[g][nsub]);
                __builtin_amdgcn_s_setprio(0);
            }
        }

        barrier_raw();                   // reads of Kt/Vt(kt) done (no drain)
        if (kt < 31) { WRITEK(); WRITEV(); }
        barrier_lds();                   // tiles (kt+1) published
    }

    // ---- final cross-k-half ctx combine (16 KB overlay on Kt/Vt) ----
    __syncthreads();
    float* red = (float*)arena;          // [64 q][64 dh] f32 = 16 KB
    if (wk == 1) {
        #pragma unroll
        for (int g = 0; g < 2; ++g)
            #pragma unroll
            for (int nsub = 0; nsub < 4; ++nsub)
                #pragma unroll
                for (int v = 0; v < 4; ++v)
                    red[(wq * 32 + g * 16 + lg * 4 + v) * 64 + nsub * 16 + ln] =
                        cacc[g][nsub][v];
    }
    __syncthreads();
    if (wk == 0) {
        #pragma unroll
        for (int g = 0; g < 2; ++g)
            #pragma unroll
            for (int nsub = 0; nsub < 4; ++nsub)
                #pragma unroll
                for (int v = 0; v < 4; ++v) {
                    float s = cacc[g][nsub][v]
                            + red[(wq * 32 + g * 16 + lg * 4 + v) * 64 + nsub * 16 + ln];
                    int sq = q0 + wq * 32 + g * 16 + lg * 4 + v;
                    ctx_out[(size_t)(b * SS + sq) * DD + h * DHH + nsub * 16 + ln] = (f16)s;
                }
    }
    #undef LOADK
    #undef WRITEK
    #undef LOADV
    #undef WRITEV
}

// ---------------- host launch ----------------
extern "C" void kernel_launch(void* const* d_in, const int* in_sizes, int n_in,
                              void* d_out, int out_size, void* d_ws, size_t ws_size,
                              hipStream_t stream)
{
    const float* query = (const float*)d_in[0];
    const float* key   = (const float*)d_in[1];
    const float* value = (const float*)d_in[2];
    const float* mask  = (const float*)d_in[3];
    const float* pen   = (const float*)d_in[4];
    const float* Wq = (const float*)d_in[6];
    const float* Wk = (const float*)d_in[7];
    const float* Wv = (const float*)d_in[8];
    const float* Wo = (const float*)d_in[9];
    const float* bo = (const float*)d_in[10];

    char* ws = (char*)d_ws;
    f16* Wqt   = (f16*)(ws);
    f16* Wkt   = (f16*)(ws + (2ull << 20));
    f16* Wvt   = (f16*)(ws + (4ull << 20));
    f16* Wot   = (f16*)(ws + (6ull << 20));
    f16* qbuf  = (f16*)(ws + (8ull << 20));
    f16* kbuf  = (f16*)(ws + (16ull << 20));
    f16* vtbuf = (f16*)(ws + (24ull << 20));
    f16* ctx   = (f16*)(ws + (32ull << 20));

    float* out_main = (float*)d_out;
    float* attn_out = (float*)d_out + (size_t)BB * SS * DD;

    wtrans_kernel<<<dim3(16, 16, 4), 256, 0, stream>>>(Wq, Wk, Wv, Wo, Wqt, Wkt, Wvt, Wot);
    gemm_qkv<<<dim3(768), 256, 0, stream>>>(query, key, value, Wqt, Wkt, Wvt, qbuf, kbuf, vtbuf);
    attn_kernel<<<dim3(1024), 256, 0, stream>>>(qbuf, kbuf, vtbuf, mask, pen, attn_out, ctx);
    gemm_out<<<dim3(256), 256, 0, stream>>>(ctx, Wot, bo, out_main);
}